// Round 1
// 243.586 us; speedup vs baseline: 1.0632x; 1.0632x over previous
//
#include <hip/hip_runtime.h>

// FWHT along axis 1 of (64, 1024, 512) fp32, unnormalized (a+b, a-b), h=1..512.
// One HBM pass: H_1024 = (H_64 (x) I_16) o (I_64 (x) H_16); stages commute.
// Round 3: DC 16->32. Each block owns FULL 128 B L2 lines (1024 rows x 32
// cols), eliminating partial-line write RMW (prev FETCH_SIZE ~ half of the
// output = RMW fills) and doubling DRAM burst contiguity. LDS 128 KB (gfx950
// has 160 KB/WG), 512 threads, grid 256 = exactly 1 block/CU (same 8 waves/CU
// as before -- occupancy limiter was LDS already). A 32-float row spans all
// 32 banks, so the transpose layout is plain row-major [1024][32]: D/E are
// 2-lanes/bank (free), C/F float4 are at the 8-cycle wave floor. Raw
// s_barrier (no vmcnt drain) + cross-tile register prefetch preserved, so
// loads/stores stay in flight across barriers (rotate waits vmcnt(16), not 0).

constexpr int NB = 64;    // batch
constexpr int NR = 1024;  // transform length (axis 1)
constexpr int ND = 512;   // inner dim
constexpr int DC = 32;    // columns per tile -> 128 B per row per block
constexpr int TPB = 512;
constexpr int GRID = 256;                     // 1 block/CU, all resident
constexpr int TPT = (NB * (ND / DC)) / GRID;  // 4 tiles per block

// Workgroup barrier WITHOUT the compiler's vmcnt(0) drain: LDS ops must be
// complete (lgkmcnt 0) but global loads/stores may remain in flight.
#define BAR() asm volatile("s_waitcnt lgkmcnt(0)\n\ts_barrier" ::: "memory")

__global__ __launch_bounds__(TPB, 2)
void fwht_kernel(const float* __restrict__ x, float* __restrict__ y) {
    __shared__ float lds[NR * DC];  // 131072 B

    const int tid = threadIdx.x;
    const int pid = blockIdx.x;     // 0..255
    const int b   = pid & 63;       // batch (invariant across tiles)
    const int dg0 = pid >> 6;       // 0..3; tile t uses dg = dg0 + 4t
                                    // siblings for batch b: pids b+64k -> same XCD (b mod 8)

    const int g  = tid >> 3;  // phase A/C/F row-group [0,64)
    const int w  = tid & 7;   // phase A/C/F col-quad  [0,8)  (w*4 in [0,32))
    const int j2 = tid >> 5;  // phase D/E row-in-group [0,16)
    const int c  = tid & 31;  // phase D/E column       [0,32)

    // base offset for loads/stores (row 16g, col quad w within the tile)
    const size_t rowA = ((size_t)b * NR + (size_t)g * 16) * ND + (size_t)(w * 4);

    // ---- preload tile 0 ----
    float4 v[16];
    {
        const float* src = x + rowA + dg0 * DC;
#pragma unroll
        for (int j = 0; j < 16; ++j)
            v[j] = *reinterpret_cast<const float4*>(src + (size_t)j * ND);
    }

#pragma unroll
    for (int t = 0; t < TPT; ++t) {
        const int dbase = (dg0 + 4 * t) * DC;

        // ---- prefetch tile t+1 (in flight across this whole iteration) ----
        float4 vn[16];
        if (t < TPT - 1) {
            const float* srcn = x + rowA + (dbase + 4 * DC);
#pragma unroll
            for (int j = 0; j < 16; ++j)
                vn[j] = *reinterpret_cast<const float4*>(srcn + (size_t)j * ND);
        }

        // ---- Pass 1: H_16 across j (stages h=1,2,4,8); waits vmcnt(16) ----
#pragma unroll
        for (int hb = 1; hb < 16; hb <<= 1) {
#pragma unroll
            for (int j = 0; j < 16; ++j) {
                if ((j & hb) == 0) {
                    const int k = j | hb;
                    float4 a = v[j], bb = v[k];
                    v[j] = make_float4(a.x + bb.x, a.y + bb.y, a.z + bb.z, a.w + bb.w);
                    v[k] = make_float4(a.x - bb.x, a.y - bb.y, a.z - bb.z, a.w - bb.w);
                }
            }
        }

        // ---- Phase C: regs -> LDS, row-major [1024][32], float4 writes ----
        // word = (16g+j)*32 + w*4; per instr: 8 g-lanes x 8 w-slots -> 8-cycle
        // wave floor (64 lanes x 16 B / 128 B/clk), balanced. No swizzle needed.
        {
            float4* lp = reinterpret_cast<float4*>(lds) + (size_t)g * 128 + w;
#pragma unroll
            for (int j = 0; j < 16; ++j)
                lp[j * 8] = v[j];
        }
        BAR();

        // ---- Phase D: LDS -> regs, one column per thread ----
        // word = i*512 + j2*32 + c -> bank = c; 2 lanes/bank (j2 pair) = free.
        float u[64];
#pragma unroll
        for (int i = 0; i < 64; ++i)
            u[i] = lds[i * 512 + j2 * 32 + c];

        // ---- Pass 2: H_64 across i (stages h=16..512) ----
#pragma unroll
        for (int hb = 1; hb < 64; hb <<= 1) {
#pragma unroll
            for (int i = 0; i < 64; ++i) {
                if ((i & hb) == 0) {
                    const int k = i | hb;
                    float a = u[i], bb = u[k];
                    u[i] = a + bb;
                    u[k] = a - bb;
                }
            }
        }
        BAR();  // all phase-D reads done before phase E overwrites

        // ---- Phase E: u -> LDS, same row-major layout (free, 2 lanes/bank) ----
#pragma unroll
        for (int i = 0; i < 64; ++i)
            lds[i * 512 + j2 * 32 + c] = u[i];
        BAR();

        // ---- Phase F: LDS -> float4 regs -> 16x global_store_dwordx4 ----
        // 8 w-lanes/row x 16 B = 128 B contiguous per row: full L2 lines, no RMW.
        {
            float* dst = y + rowA + dbase;
            const float4* lp = reinterpret_cast<const float4*>(lds) + (size_t)g * 128 + w;
#pragma unroll
            for (int j = 0; j < 16; ++j)
                *reinterpret_cast<float4*>(dst + (size_t)j * ND) = lp[j * 8];
        }
        BAR();  // all phase-F reads done before next iter's phase-C writes

        // ---- rotate prefetch buffer ----
        if (t < TPT - 1) {
#pragma unroll
            for (int j = 0; j < 16; ++j) v[j] = vn[j];
        }
    }
}

extern "C" void kernel_launch(void* const* d_in, const int* in_sizes, int n_in,
                              void* d_out, int out_size, void* d_ws, size_t ws_size,
                              hipStream_t stream) {
    const float* x = (const float*)d_in[0];
    float* y = (float*)d_out;
    fwht_kernel<<<dim3(GRID), dim3(TPB), 0, stream>>>(x, y);
}